// Round 9
// baseline (227.515 us; speedup 1.0000x reference)
//
#include <hip/hip_runtime.h>
#include <hip/hip_bf16.h>

// LocalAttn: B=8 S=1024 E=512 H=16 D=32, rel-pos bias, NO causal mask.
// f32 inputs / f32 output. Internals bf16 for MFMA.
// R9: TWO kernels only (launch overhead ~13-17us each per R7/R8 algebra).
// proj loads x/W as f32 + in-reg RNE pack (convert kernel deleted; Er
// conversion folded into proj as 64 extra WGs). Q/K/Er stored
// pair-interleaved u32 (d,d+16): same sigma k-permutation on both QK MFMA
// operands -> S unchanged, attn byte addressing unchanged, proj epilogue
// 32x4B stores instead of 64x2B. Attn = R6 + ones-B MFMA row-sums.

typedef short bf16x8 __attribute__((ext_vector_type(8)));   // 8 bf16 (4 VGPRs)
typedef float f32x4 __attribute__((ext_vector_type(4)));
typedef unsigned short u16x4 __attribute__((ext_vector_type(4)));
typedef unsigned int u32x4 __attribute__((ext_vector_type(4)));

#if __has_builtin(__builtin_amdgcn_exp2f)
#define EXP2F(x) __builtin_amdgcn_exp2f(x)
#else
#define EXP2F(x) exp2f(x)
#endif

constexpr int Bb = 8, Ss = 1024, Ee = 512, Hh = 16, Dd = 32;
// log2(e)/sqrt(32): folds the 1/sqrt(D) softmax scale and exp->exp2 into Q.
#define QSCALE 0.25503486f

__device__ __forceinline__ bf16x8 ldg_frag(const __hip_bfloat16* p) {
    return *reinterpret_cast<const bf16x8*>(p);
}

__device__ __forceinline__ unsigned short bf16_bits(float v) {
    return __builtin_bit_cast(unsigned short, __float2bfloat16(v));
}

__device__ __forceinline__ unsigned pack_bf16(float lo, float hi) {
    return (unsigned)bf16_bits(lo) | ((unsigned)bf16_bits(hi) << 16);
}

__device__ __forceinline__ float bperm_f(int addr, float v) {
    return __builtin_bit_cast(float,
        __builtin_amdgcn_ds_bpermute(addr, __builtin_bit_cast(int, v)));
}

// load 8 consecutive f32, convert (RNE) to a bf16x8 MFMA fragment
__device__ __forceinline__ bf16x8 ldg_f32_frag(const float* p) {
    const float4 a = *reinterpret_cast<const float4*>(p);
    const float4 b = *reinterpret_cast<const float4*>(p + 4);
    u32x4 pk;
    pk[0] = pack_bf16(a.x, a.y);
    pk[1] = pack_bf16(a.z, a.w);
    pk[2] = pack_bf16(b.x, b.y);
    pk[3] = pack_bf16(b.z, b.w);
    return __builtin_bit_cast(bf16x8, pk);
}

// ---------------- projection: Q/K/V = x @ W^T (f32 in) + Er convert -------
// ids 0..767: by = id & 127 (64-row x block), bx = id >> 7 (0..5).
// id % 8 == by % 8 -> all 6 col-blocks of one by on the SAME XCD; per-XCD
// x f32 slice 2 MB + W stream -> x L2-resident, read once from HBM.
// ids 768..831: Er f32 -> pair-interleaved bf16 (row 2047 zeroed).
#define PROJ_MFMA(A, B) do {                                          \
    _Pragma("unroll")                                                 \
    for (int rf = 0; rf < 4; ++rf)                                    \
        _Pragma("unroll")                                             \
        for (int t = 0; t < 4; ++t)                                   \
            acc[rf][t] = __builtin_amdgcn_mfma_f32_16x16x32_bf16(     \
                A[rf], B[t], acc[rf][t], 0, 0, 0);                    \
} while (0)

__global__ __launch_bounds__(256) void proj_kernel(
    const float* __restrict__ x,    // [8192][512]
    const float* __restrict__ wq,   // [512][512] each
    const float* __restrict__ wk,
    const float* __restrict__ wv,
    const float* __restrict__ er,   // [2047][32]
    unsigned* __restrict__ Qs32,    // [B][H][S][16] u32 pair-interleaved
    unsigned* __restrict__ Kh32,    // [B][H][S][16] u32 pair-interleaved
    unsigned* __restrict__ Vt32,    // [B][H][D][512] u32 interleaved
    unsigned* __restrict__ erb32)   // [2048][16] u32 pair-interleaved
{
    const int tid = threadIdx.x;

    if (blockIdx.x >= 768) {        // ---- Er convert WGs ----
        const int id2 = (blockIdx.x - 768) * 256 + tid;   // 0..16383
        #pragma unroll
        for (int p = 0; p < 2; ++p) {
            const int s   = id2 * 2 + p;       // u32 slot 0..32767
            const int row = s >> 4;
            const int j   = s & 15;
            unsigned val = 0;
            if (row < 2047)
                val = pack_bf16(er[row * 32 + j], er[row * 32 + j + 16]);
            erb32[s] = val;
        }
        return;
    }

    const int wave = tid >> 6;
    const int lane = tid & 63;
    const int li   = lane & 15;
    const int quad = lane >> 4;

    const int by = blockIdx.x & 127;
    const int bx = blockIdx.x >> 7;          // 0..5
    const int m0    = by * 64;
    const int nbase = bx * 256 + wave * 64;
    const int mat   = nbase >> 9;            // 0=Q 1=K 2=V (uniform per wave)
    const int nn0   = nbase & 511;
    const float* W  = (mat == 0) ? wq : (mat == 1) ? wk : wv;

    f32x4 acc[4][4];
    #pragma unroll
    for (int rf = 0; rf < 4; ++rf)
        #pragma unroll
        for (int t = 0; t < 4; ++t) acc[rf][t] = f32x4{0.f, 0.f, 0.f, 0.f};

    const float* xp = x + (size_t)(m0 + li) * Ee + quad * 8;
    const float* wp = W + (size_t)(nn0 + li) * Ee + quad * 8;

    for (int k0 = 0; k0 < Ee; k0 += 32) {
        bf16x8 a[4], b[4];
        #pragma unroll
        for (int rf = 0; rf < 4; ++rf) a[rf] = ldg_f32_frag(xp + rf * 16 * Ee + k0);
        #pragma unroll
        for (int t = 0; t < 4; ++t)    b[t]  = ldg_f32_frag(wp + t * 16 * Ee + k0);
        PROJ_MFMA(a, b);
    }

    // epilogue. C layout: col = li, row = quad*4 + reg.
    const int bb = m0 >> 10;           // 64-row block never straddles b
    const int sb = m0 & 1023;
    if (mat == 2) {
        #pragma unroll
        for (int t = 0; t < 4; ++t) {
            int nn = nn0 + t * 16 + li;
            int h = nn >> 5, d = nn & 31;
            size_t base = ((size_t)(bb * Hh + h) * Dd + d) * 512
                        + (sb >> 5) * 16 + quad * 4;
            #pragma unroll
            for (int p = 0; p < 2; ++p) {      // rf pair (2p, 2p+1)
                u32x4 pk;
                #pragma unroll
                for (int r = 0; r < 4; ++r)
                    pk[r] = pack_bf16(acc[2*p][t][r], acc[2*p+1][t][r]);
                *reinterpret_cast<u32x4*>(Vt32 + base + (size_t)p * 16) = pk;
            }
        }
    } else {
        // Q/K pair-interleaved: u32 slot li of head h packs (d=li, d=li+16);
        // t pairs (0,1) -> head h0, (2,3) -> head h0+1.
        unsigned* dst = (mat == 0) ? Qs32 : Kh32;
        const float sc = (mat == 0) ? QSCALE : 1.0f;
        const int h0 = nn0 >> 5;
        #pragma unroll
        for (int rf = 0; rf < 4; ++rf) {
            #pragma unroll
            for (int r = 0; r < 4; ++r) {
                const int srow = sb + rf * 16 + quad * 4 + r;
                #pragma unroll
                for (int hp = 0; hp < 2; ++hp)
                    dst[((size_t)(bb * Hh + h0 + hp) * Ss + srow) * 16 + li] =
                        pack_bf16(acc[rf][2*hp][r] * sc, acc[rf][2*hp+1][r] * sc);
            }
        }
    }
}

// ---------------- attention (R6 + ones-MFMA row sums) ----------------------
// grid 1024; (b,h) = blockIdx&127 (XCD-local), ib = blockIdx>>7.
// Wave owns TWO 16-row Q strips (32 rows); j-loop steps 64.
// Srel: band MFMA C-frags rotated intra-quad via ds_bpermute.
// Row sums: OL = P . ones via MFMA (every col = rowsum) -> no VALU adds,
// no epilogue shuffle tree.
__global__ __launch_bounds__(256) void attn_kernel(
    const __hip_bfloat16* __restrict__ Qs,
    const __hip_bfloat16* __restrict__ Kh,
    const __hip_bfloat16* __restrict__ Vt,   // bf16 views (byte layout same)
    const __hip_bfloat16* __restrict__ Er,   // [2048][32]-bytes, row 2047 = 0
    float* __restrict__ out)                 // [B][S][E] f32
{
    const int tid  = threadIdx.x;
    const int wave = tid >> 6;
    const int lane = tid & 63;
    const int li   = lane & 15;
    const int quad = lane >> 4;

    const int c  = blockIdx.x & 127;
    const int b  = c >> 4;
    const int h  = c & 15;
    const int ib = blockIdx.x >> 7;          // 0..7
    const int i0 = ib * 128 + wave * 32;     // strip A rows i0.., B rows i0+16..

    const __hip_bfloat16* Qp = Qs + (size_t)(b * Hh + h) * Ss * Dd;
    const __hip_bfloat16* Kp = Kh + (size_t)(b * Hh + h) * Ss * Dd;
    const __hip_bfloat16* Vp = Vt + (size_t)(b * Hh + h) * Dd * Ss;

    __shared__ unsigned pb_lds[4][4][16 * 20];   // 20480 B total
    unsigned* pbA0 = pb_lds[wave][0];
    unsigned* pbA1 = pb_lds[wave][1];
    unsigned* pbB0 = pb_lds[wave][2];
    unsigned* pbB1 = pb_lds[wave][3];

    const bf16x8 qfA = ldg_frag(Qp + (i0      + li) * Dd + quad * 8);
    const bf16x8 qfB = ldg_frag(Qp + (i0 + 16 + li) * Dd + quad * 8);

    int addr4[4];
    bool cond[4];
    #pragma unroll
    for (int r = 0; r < 4; ++r) {
        const int row = quad * 4 + r;
        addr4[r] = (16 * quad + ((li - row + 15) & 15)) * 4;
        cond[r]  = (li <= row);            // bc < 16 -> lower band block
    }
    const int pbw = quad * 80 + li;        // pb write base (u32)
    const int pbr = li * 20 + quad * 4;    // pb read base (16B aligned)

    const bf16x8 onesb = {16256,16256,16256,16256,16256,16256,16256,16256};
    const f32x4 zero = f32x4{0,0,0,0};
    f32x4 oA0 = zero, oA1 = zero, oB0 = zero, oB1 = zero;
    f32x4 oLA = zero, oLB = zero;          // row sums via ones-MFMA

    for (int j0 = 0; j0 < Ss; j0 += 64) {
        bf16x8 k0 = ldg_frag(Kp + (j0      + li) * Dd + quad * 8);
        bf16x8 k1 = ldg_frag(Kp + (j0 + 16 + li) * Dd + quad * 8);
        bf16x8 k2 = ldg_frag(Kp + (j0 + 32 + li) * Dd + quad * 8);
        bf16x8 k3 = ldg_frag(Kp + (j0 + 48 + li) * Dd + quad * 8);
        const int rb = j0 - i0 + 1008;       // strip A base; rb-16 >= 0
        bf16x8 em = ldg_frag(Er + (rb - 16 + li) * Dd + quad * 8);
        bf16x8 e0 = ldg_frag(Er + (rb      + li) * Dd + quad * 8);
        bf16x8 e1 = ldg_frag(Er + (rb + 16 + li) * Dd + quad * 8);
        bf16x8 e2 = ldg_frag(Er + (rb + 32 + li) * Dd + quad * 8);
        bf16x8 e3 = ldg_frag(Er + (rb + 48 + li) * Dd + quad * 8);
        bf16x8 e4 = ldg_frag(Er + (rb + 64 + li) * Dd + quad * 8);
        bf16x8 v0 = ldg_frag(Vp + (li     ) * Ss + j0 + quad * 8);
        bf16x8 v1 = ldg_frag(Vp + (li + 16) * Ss + j0 + quad * 8);
        bf16x8 v2 = ldg_frag(Vp + (li     ) * Ss + j0 + 32 + quad * 8);
        bf16x8 v3 = ldg_frag(Vp + (li + 16) * Ss + j0 + 32 + quad * 8);

        // ================= strip A (rows i0..i0+15) =================
        {
            f32x4 s0 = __builtin_amdgcn_mfma_f32_16x16x32_bf16(qfA, k0, zero, 0, 0, 0);
            f32x4 s1 = __builtin_amdgcn_mfma_f32_16x16x32_bf16(qfA, k1, zero, 0, 0, 0);
            f32x4 s2 = __builtin_amdgcn_mfma_f32_16x16x32_bf16(qfA, k2, zero, 0, 0, 0);
            f32x4 s3 = __builtin_amdgcn_mfma_f32_16x16x32_bf16(qfA, k3, zero, 0, 0, 0);
            f32x4 q0 = __builtin_amdgcn_mfma_f32_16x16x32_bf16(qfA, e0, zero, 0, 0, 0);
            f32x4 q1 = __builtin_amdgcn_mfma_f32_16x16x32_bf16(qfA, e1, zero, 0, 0, 0);
            f32x4 q2 = __builtin_amdgcn_mfma_f32_16x16x32_bf16(qfA, e2, zero, 0, 0, 0);
            f32x4 q3 = __builtin_amdgcn_mfma_f32_16x16x32_bf16(qfA, e3, zero, 0, 0, 0);
            f32x4 q4 = __builtin_amdgcn_mfma_f32_16x16x32_bf16(qfA, e4, zero, 0, 0, 0);
            float p0[4], p1[4], p2[4], p3[4];
            #pragma unroll
            for (int r = 0; r < 4; ++r) {
                float f0 = bperm_f(addr4[r], q0[r]);
                float f1 = bperm_f(addr4[r], q1[r]);
                float f2 = bperm_f(addr4[r], q2[r]);
                float f3 = bperm_f(addr4[r], q3[r]);
                float f4 = bperm_f(addr4[r], q4[r]);
                p0[r] = EXP2F(s0[r] + (cond[r] ? f0 : f1));
                p1[r] = EXP2F(s1[r] + (cond[r] ? f1 : f2));
                p2[r] = EXP2F(s2[r] + (cond[r] ? f2 : f3));
                p3[r] = EXP2F(s3[r] + (cond[r] ? f3 : f4));
            }
            #pragma unroll
            for (int r = 0; r < 4; ++r) {
                pbA0[pbw + 20 * r] = pack_bf16(p0[r], p1[r]);
                pbA1[pbw + 20 * r] = pack_bf16(p2[r], p3[r]);
            }
            bf16x8 pf0 = *reinterpret_cast<const bf16x8*>(&pbA0[pbr]);
            bf16x8 pf1 = *reinterpret_cast<const bf16x8*>(&pbA1[pbr]);
            oA0 = __builtin_amdgcn_mfma_f32_16x16x32_bf16(pf0, v0, oA0, 0, 0, 0);
            oA1 = __builtin_amdgcn_mfma_f32_16x16x32_bf16(pf0, v1, oA1, 0, 0, 0);
            oLA = __builtin_amdgcn_mfma_f32_16x16x32_bf16(pf0, onesb, oLA, 0, 0, 0);
            oA0 = __builtin_amdgcn_mfma_f32_16x16x32_bf16(pf1, v2, oA0, 0, 0, 0);
            oA1 = __builtin_amdgcn_mfma_f32_16x16x32_bf16(pf1, v3, oA1, 0, 0, 0);
            oLA = __builtin_amdgcn_mfma_f32_16x16x32_bf16(pf1, onesb, oLA, 0, 0, 0);
        }

        // ================= strip B (rows i0+16..i0+31) ==============
        {
            f32x4 s0 = __builtin_amdgcn_mfma_f32_16x16x32_bf16(qfB, k0, zero, 0, 0, 0);
            f32x4 s1 = __builtin_amdgcn_mfma_f32_16x16x32_bf16(qfB, k1, zero, 0, 0, 0);
            f32x4 s2 = __builtin_amdgcn_mfma_f32_16x16x32_bf16(qfB, k2, zero, 0, 0, 0);
            f32x4 s3 = __builtin_amdgcn_mfma_f32_16x16x32_bf16(qfB, k3, zero, 0, 0, 0);
            f32x4 q0 = __builtin_amdgcn_mfma_f32_16x16x32_bf16(qfB, em, zero, 0, 0, 0);
            f32x4 q1 = __builtin_amdgcn_mfma_f32_16x16x32_bf16(qfB, e0, zero, 0, 0, 0);
            f32x4 q2 = __builtin_amdgcn_mfma_f32_16x16x32_bf16(qfB, e1, zero, 0, 0, 0);
            f32x4 q3 = __builtin_amdgcn_mfma_f32_16x16x32_bf16(qfB, e2, zero, 0, 0, 0);
            f32x4 q4 = __builtin_amdgcn_mfma_f32_16x16x32_bf16(qfB, e3, zero, 0, 0, 0);
            float p0[4], p1[4], p2[4], p3[4];
            #pragma unroll
            for (int r = 0; r < 4; ++r) {
                float f0 = bperm_f(addr4[r], q0[r]);
                float f1 = bperm_f(addr4[r], q1[r]);
                float f2 = bperm_f(addr4[r], q2[r]);
                float f3 = bperm_f(addr4[r], q3[r]);
                float f4 = bperm_f(addr4[r], q4[r]);
                p0[r] = EXP2F(s0[r] + (cond[r] ? f0 : f1));
                p1[r] = EXP2F(s1[r] + (cond[r] ? f1 : f2));
                p2[r] = EXP2F(s2[r] + (cond[r] ? f2 : f3));
                p3[r] = EXP2F(s3[r] + (cond[r] ? f3 : f4));
            }
            #pragma unroll
            for (int r = 0; r < 4; ++r) {
                pbB0[pbw + 20 * r] = pack_bf16(p0[r], p1[r]);
                pbB1[pbw + 20 * r] = pack_bf16(p2[r], p3[r]);
            }
            bf16x8 pf0 = *reinterpret_cast<const bf16x8*>(&pbB0[pbr]);
            bf16x8 pf1 = *reinterpret_cast<const bf16x8*>(&pbB1[pbr]);
            oB0 = __builtin_amdgcn_mfma_f32_16x16x32_bf16(pf0, v0, oB0, 0, 0, 0);
            oB1 = __builtin_amdgcn_mfma_f32_16x16x32_bf16(pf0, v1, oB1, 0, 0, 0);
            oLB = __builtin_amdgcn_mfma_f32_16x16x32_bf16(pf0, onesb, oLB, 0, 0, 0);
            oB0 = __builtin_amdgcn_mfma_f32_16x16x32_bf16(pf1, v2, oB0, 0, 0, 0);
            oB1 = __builtin_amdgcn_mfma_f32_16x16x32_bf16(pf1, v3, oB1, 0, 0, 0);
            oLB = __builtin_amdgcn_mfma_f32_16x16x32_bf16(pf1, onesb, oLB, 0, 0, 0);
        }
    }

    // normalize and store (oL[r] holds the row sum in every column)
    #pragma unroll
    for (int r = 0; r < 4; ++r) {
        const float ia  = 1.0f / oLA[r];
        const float ib2 = 1.0f / oLB[r];
        const int srowA = i0 + quad * 4 + r;
        float* opA = out + ((size_t)b * Ss + srowA) * Ee + h * Dd;
        opA[li]      = oA0[r] * ia;
        opA[16 + li] = oA1[r] * ia;
        float* opB = opA + 16 * Ee;          // srowA + 16
        opB[li]      = oB0[r] * ib2;
        opB[16 + li] = oB1[r] * ib2;
    }
}

extern "C" void kernel_launch(void* const* d_in, const int* in_sizes, int n_in,
                              void* d_out, int out_size, void* d_ws, size_t ws_size,
                              hipStream_t stream) {
    const float* x  = (const float*)d_in[0];
    const float* Wq = (const float*)d_in[1];
    const float* Wk = (const float*)d_in[2];
    const float* Wv = (const float*)d_in[3];
    const float* Er = (const float*)d_in[4];
    float* out = (float*)d_out;

    // ws layout (bf16 elements; all offsets 16B-aligned)
    __hip_bfloat16* erb = reinterpret_cast<__hip_bfloat16*>(d_ws);  // [2048][32]
    __hip_bfloat16* Qs  = erb + 65536;
    __hip_bfloat16* Kh  = Qs  + (size_t)Bb * Hh * Ss * Dd;
    __hip_bfloat16* Vt  = Kh  + (size_t)Bb * Hh * Ss * Dd;

    proj_kernel<<<dim3(832), 256, 0, stream>>>(
        x, Wq, Wk, Wv, Er,
        reinterpret_cast<unsigned*>(Qs), reinterpret_cast<unsigned*>(Kh),
        reinterpret_cast<unsigned*>(Vt), reinterpret_cast<unsigned*>(erb));
    attn_kernel<<<dim3(1024), 256, 0, stream>>>(Qs, Kh, Vt, erb, out);
}

// Round 10
// 227.316 us; speedup vs baseline: 1.0009x; 1.0009x over previous
//
#include <hip/hip_runtime.h>
#include <hip/hip_bf16.h>

// LocalAttn: B=8 S=1024 E=512 H=16 D=32, rel-pos bias, NO causal mask.
// f32 inputs / f32 output. Internals bf16 for MFMA.
// R10: proj fixed for register starvation (R9: VGPR=72, acc used 64 ->
// loads fully serialized at memory latency, 94us). Now launch_bounds
// (256,2) + explicit raw-f32 ping-pong (pack k, issue k+1 loads, MFMA k)
// keeps ~16 loads in flight. Attn reverted to exact R6 body (81.8us);
// Q/K/Er remain pair-interleaved u32 (sigma k-perm, proven in R9).

typedef short bf16x8 __attribute__((ext_vector_type(8)));   // 8 bf16 (4 VGPRs)
typedef float f32x4 __attribute__((ext_vector_type(4)));
typedef unsigned short u16x4 __attribute__((ext_vector_type(4)));
typedef unsigned int u32x4 __attribute__((ext_vector_type(4)));

#if __has_builtin(__builtin_amdgcn_exp2f)
#define EXP2F(x) __builtin_amdgcn_exp2f(x)
#else
#define EXP2F(x) exp2f(x)
#endif

constexpr int Bb = 8, Ss = 1024, Ee = 512, Hh = 16, Dd = 32;
// log2(e)/sqrt(32): folds the 1/sqrt(D) softmax scale and exp->exp2 into Q.
#define QSCALE 0.25503486f

__device__ __forceinline__ bf16x8 ldg_frag(const __hip_bfloat16* p) {
    return *reinterpret_cast<const bf16x8*>(p);
}

__device__ __forceinline__ unsigned short bf16_bits(float v) {
    return __builtin_bit_cast(unsigned short, __float2bfloat16(v));
}

__device__ __forceinline__ unsigned pack_bf16(float lo, float hi) {
    return (unsigned)bf16_bits(lo) | ((unsigned)bf16_bits(hi) << 16);
}

__device__ __forceinline__ float bperm_f(int addr, float v) {
    return __builtin_bit_cast(float,
        __builtin_amdgcn_ds_bpermute(addr, __builtin_bit_cast(int, v)));
}

__device__ __forceinline__ bf16x8 pack_frag(const float4 lo, const float4 hi) {
    u32x4 pk;
    pk[0] = pack_bf16(lo.x, lo.y);
    pk[1] = pack_bf16(lo.z, lo.w);
    pk[2] = pack_bf16(hi.x, hi.y);
    pk[3] = pack_bf16(hi.z, hi.w);
    return __builtin_bit_cast(bf16x8, pk);
}

// ---------------- projection: Q/K/V = x @ W^T (f32 in) + Er convert -------
// ids 0..767: by = id & 127 (64-row x block), bx = id >> 7 (0..5).
// id % 8 == by % 8 -> all 6 col-blocks of one by on the SAME XCD.
// ids 768..831: Er f32 -> pair-interleaved bf16 (row 2047 zeroed).
// K-loop: raw-float4 ping-pong; launch_bounds(256,2) so acc(64) + raw(64)
// + frags(32) + ptrs fit without serializing loads.
__global__ __launch_bounds__(256, 2) void proj_kernel(
    const float* __restrict__ x,    // [8192][512]
    const float* __restrict__ wq,   // [512][512] each
    const float* __restrict__ wk,
    const float* __restrict__ wv,
    const float* __restrict__ er,   // [2047][32]
    unsigned* __restrict__ Qs32,    // [B][H][S][16] u32 pair-interleaved
    unsigned* __restrict__ Kh32,    // [B][H][S][16] u32 pair-interleaved
    unsigned* __restrict__ Vt32,    // [B][H][D][512] u32 interleaved
    unsigned* __restrict__ erb32)   // [2048][16] u32 pair-interleaved
{
    const int tid = threadIdx.x;

    if (blockIdx.x >= 768) {        // ---- Er convert WGs ----
        const int id2 = (blockIdx.x - 768) * 256 + tid;   // 0..16383
        #pragma unroll
        for (int p = 0; p < 2; ++p) {
            const int s   = id2 * 2 + p;       // u32 slot 0..32767
            const int row = s >> 4;
            const int j   = s & 15;
            unsigned val = 0;
            if (row < 2047)
                val = pack_bf16(er[row * 32 + j], er[row * 32 + j + 16]);
            erb32[s] = val;
        }
        return;
    }

    const int wave = tid >> 6;
    const int lane = tid & 63;
    const int li   = lane & 15;
    const int quad = lane >> 4;

    const int by = blockIdx.x & 127;
    const int bx = blockIdx.x >> 7;          // 0..5
    const int m0    = by * 64;
    const int nbase = bx * 256 + wave * 64;
    const int mat   = nbase >> 9;            // 0=Q 1=K 2=V (uniform per wave)
    const int nn0   = nbase & 511;
    const float* W  = (mat == 0) ? wq : (mat == 1) ? wk : wv;

    f32x4 acc[4][4];
    #pragma unroll
    for (int rf = 0; rf < 4; ++rf)
        #pragma unroll
        for (int t = 0; t < 4; ++t) acc[rf][t] = f32x4{0.f, 0.f, 0.f, 0.f};

    // rolling row pointers (one per 16-row frag block)
    const float* xr[4];
    const float* wr[4];
    #pragma unroll
    for (int i = 0; i < 4; ++i) {
        xr[i] = x + (size_t)(m0 + i * 16 + li) * Ee + quad * 8;
        wr[i] = W + (size_t)(nn0 + i * 16 + li) * Ee + quad * 8;
    }

    float4 rA[4][2], rB[4][2];
    #pragma unroll
    for (int i = 0; i < 4; ++i) {
        rA[i][0] = *reinterpret_cast<const float4*>(xr[i]);
        rA[i][1] = *reinterpret_cast<const float4*>(xr[i] + 4);
        rB[i][0] = *reinterpret_cast<const float4*>(wr[i]);
        rB[i][1] = *reinterpret_cast<const float4*>(wr[i] + 4);
    }

    for (int k0 = 0; k0 < 16; ++k0) {
        // pack current raws into MFMA frags (frees raw regs for next loads)
        bf16x8 a[4], b[4];
        #pragma unroll
        for (int i = 0; i < 4; ++i) {
            a[i] = pack_frag(rA[i][0], rA[i][1]);
            b[i] = pack_frag(rB[i][0], rB[i][1]);
        }
        // issue next iteration's 16 loads (in flight across the MFMAs)
        if (k0 < 15) {
            #pragma unroll
            for (int i = 0; i < 4; ++i) {
                xr[i] += 32; wr[i] += 32;
                rA[i][0] = *reinterpret_cast<const float4*>(xr[i]);
                rA[i][1] = *reinterpret_cast<const float4*>(xr[i] + 4);
                rB[i][0] = *reinterpret_cast<const float4*>(wr[i]);
                rB[i][1] = *reinterpret_cast<const float4*>(wr[i] + 4);
            }
        }
        #pragma unroll
        for (int rf = 0; rf < 4; ++rf)
            #pragma unroll
            for (int t = 0; t < 4; ++t)
                acc[rf][t] = __builtin_amdgcn_mfma_f32_16x16x32_bf16(
                    a[rf], b[t], acc[rf][t], 0, 0, 0);
    }

    // epilogue. C layout: col = li, row = quad*4 + reg.
    const int bb = m0 >> 10;           // 64-row block never straddles b
    const int sb = m0 & 1023;
    if (mat == 2) {
        #pragma unroll
        for (int t = 0; t < 4; ++t) {
            int nn = nn0 + t * 16 + li;
            int h = nn >> 5, d = nn & 31;
            size_t base = ((size_t)(bb * Hh + h) * Dd + d) * 512
                        + (sb >> 5) * 16 + quad * 4;
            #pragma unroll
            for (int p = 0; p < 2; ++p) {      // rf pair (2p, 2p+1)
                u32x4 pk;
                #pragma unroll
                for (int r = 0; r < 4; ++r)
                    pk[r] = pack_bf16(acc[2*p][t][r], acc[2*p+1][t][r]);
                *reinterpret_cast<u32x4*>(Vt32 + base + (size_t)p * 16) = pk;
            }
        }
    } else {
        // Q/K pair-interleaved: u32 slot li of head h packs (d=li, d=li+16)
        unsigned* dst = (mat == 0) ? Qs32 : Kh32;
        const float sc = (mat == 0) ? QSCALE : 1.0f;
        const int h0 = nn0 >> 5;
        #pragma unroll
        for (int rf = 0; rf < 4; ++rf) {
            #pragma unroll
            for (int r = 0; r < 4; ++r) {
                const int srow = sb + rf * 16 + quad * 4 + r;
                #pragma unroll
                for (int hp = 0; hp < 2; ++hp)
                    dst[((size_t)(bb * Hh + h0 + hp) * Ss + srow) * 16 + li] =
                        pack_bf16(acc[rf][2*hp][r] * sc, acc[rf][2*hp+1][r] * sc);
            }
        }
    }
}

// ---------------- attention (exact R6 body, 81.8us) ------------------------
// grid 1024; (b,h) = blockIdx&127 (XCD-local), ib = blockIdx>>7.
// Wave owns TWO 16-row Q strips (32 rows); j-loop steps 64.
// Srel: band MFMA C-frags rotated intra-quad via ds_bpermute.
__global__ __launch_bounds__(256) void attn_kernel(
    const __hip_bfloat16* __restrict__ Qs,
    const __hip_bfloat16* __restrict__ Kh,
    const __hip_bfloat16* __restrict__ Vt,   // bf16 views (byte layout same)
    const __hip_bfloat16* __restrict__ Er,   // [2048][32]-bytes, row 2047 = 0
    float* __restrict__ out)                 // [B][S][E] f32
{
    const int tid  = threadIdx.x;
    const int wave = tid >> 6;
    const int lane = tid & 63;
    const int li   = lane & 15;
    const int quad = lane >> 4;

    const int c  = blockIdx.x & 127;
    const int b  = c >> 4;
    const int h  = c & 15;
    const int ib = blockIdx.x >> 7;          // 0..7
    const int i0 = ib * 128 + wave * 32;     // strip A rows i0.., B rows i0+16..

    const __hip_bfloat16* Qp = Qs + (size_t)(b * Hh + h) * Ss * Dd;
    const __hip_bfloat16* Kp = Kh + (size_t)(b * Hh + h) * Ss * Dd;
    const __hip_bfloat16* Vp = Vt + (size_t)(b * Hh + h) * Dd * Ss;

    __shared__ unsigned pb_lds[4][4][16 * 20];   // 20480 B total
    unsigned* pbA0 = pb_lds[wave][0];
    unsigned* pbA1 = pb_lds[wave][1];
    unsigned* pbB0 = pb_lds[wave][2];
    unsigned* pbB1 = pb_lds[wave][3];

    const bf16x8 qfA = ldg_frag(Qp + (i0      + li) * Dd + quad * 8);
    const bf16x8 qfB = ldg_frag(Qp + (i0 + 16 + li) * Dd + quad * 8);

    int addr4[4];
    bool cond[4];
    #pragma unroll
    for (int r = 0; r < 4; ++r) {
        const int row = quad * 4 + r;
        addr4[r] = (16 * quad + ((li - row + 15) & 15)) * 4;
        cond[r]  = (li <= row);            // bc < 16 -> lower band block
    }
    const int pbw = quad * 80 + li;        // pb write base (u32)
    const int pbr = li * 20 + quad * 4;    // pb read base (16B aligned)

    f32x4 oA0 = f32x4{0,0,0,0}, oA1 = f32x4{0,0,0,0};
    f32x4 oB0 = f32x4{0,0,0,0}, oB1 = f32x4{0,0,0,0};
    float lsumA[4] = {0,0,0,0}, lsumB[4] = {0,0,0,0};
    const f32x4 zero = f32x4{0,0,0,0};

    for (int j0 = 0; j0 < Ss; j0 += 64) {
        bf16x8 k0 = ldg_frag(Kp + (j0      + li) * Dd + quad * 8);
        bf16x8 k1 = ldg_frag(Kp + (j0 + 16 + li) * Dd + quad * 8);
        bf16x8 k2 = ldg_frag(Kp + (j0 + 32 + li) * Dd + quad * 8);
        bf16x8 k3 = ldg_frag(Kp + (j0 + 48 + li) * Dd + quad * 8);
        const int rb = j0 - i0 + 1008;       // strip A base; rb-16 >= 0
        bf16x8 em = ldg_frag(Er + (rb - 16 + li) * Dd + quad * 8);
        bf16x8 e0 = ldg_frag(Er + (rb      + li) * Dd + quad * 8);
        bf16x8 e1 = ldg_frag(Er + (rb + 16 + li) * Dd + quad * 8);
        bf16x8 e2 = ldg_frag(Er + (rb + 32 + li) * Dd + quad * 8);
        bf16x8 e3 = ldg_frag(Er + (rb + 48 + li) * Dd + quad * 8);
        bf16x8 e4 = ldg_frag(Er + (rb + 64 + li) * Dd + quad * 8);
        bf16x8 v0 = ldg_frag(Vp + (li     ) * Ss + j0 + quad * 8);
        bf16x8 v1 = ldg_frag(Vp + (li + 16) * Ss + j0 + quad * 8);
        bf16x8 v2 = ldg_frag(Vp + (li     ) * Ss + j0 + 32 + quad * 8);
        bf16x8 v3 = ldg_frag(Vp + (li + 16) * Ss + j0 + 32 + quad * 8);

        // ================= strip A (rows i0..i0+15) =================
        {
            f32x4 s0 = __builtin_amdgcn_mfma_f32_16x16x32_bf16(qfA, k0, zero, 0, 0, 0);
            f32x4 s1 = __builtin_amdgcn_mfma_f32_16x16x32_bf16(qfA, k1, zero, 0, 0, 0);
            f32x4 s2 = __builtin_amdgcn_mfma_f32_16x16x32_bf16(qfA, k2, zero, 0, 0, 0);
            f32x4 s3 = __builtin_amdgcn_mfma_f32_16x16x32_bf16(qfA, k3, zero, 0, 0, 0);
            f32x4 q0 = __builtin_amdgcn_mfma_f32_16x16x32_bf16(qfA, e0, zero, 0, 0, 0);
            f32x4 q1 = __builtin_amdgcn_mfma_f32_16x16x32_bf16(qfA, e1, zero, 0, 0, 0);
            f32x4 q2 = __builtin_amdgcn_mfma_f32_16x16x32_bf16(qfA, e2, zero, 0, 0, 0);
            f32x4 q3 = __builtin_amdgcn_mfma_f32_16x16x32_bf16(qfA, e3, zero, 0, 0, 0);
            f32x4 q4 = __builtin_amdgcn_mfma_f32_16x16x32_bf16(qfA, e4, zero, 0, 0, 0);
            float p0[4], p1[4], p2[4], p3[4];
            #pragma unroll
            for (int r = 0; r < 4; ++r) {
                float f0 = bperm_f(addr4[r], q0[r]);
                float f1 = bperm_f(addr4[r], q1[r]);
                float f2 = bperm_f(addr4[r], q2[r]);
                float f3 = bperm_f(addr4[r], q3[r]);
                float f4 = bperm_f(addr4[r], q4[r]);
                p0[r] = EXP2F(s0[r] + (cond[r] ? f0 : f1));
                p1[r] = EXP2F(s1[r] + (cond[r] ? f1 : f2));
                p2[r] = EXP2F(s2[r] + (cond[r] ? f2 : f3));
                p3[r] = EXP2F(s3[r] + (cond[r] ? f3 : f4));
                lsumA[r] += (p0[r] + p1[r]) + (p2[r] + p3[r]);
            }
            #pragma unroll
            for (int r = 0; r < 4; ++r) {
                pbA0[pbw + 20 * r] = pack_bf16(p0[r], p1[r]);
                pbA1[pbw + 20 * r] = pack_bf16(p2[r], p3[r]);
            }
            bf16x8 pf0 = *reinterpret_cast<const bf16x8*>(&pbA0[pbr]);
            bf16x8 pf1 = *reinterpret_cast<const bf16x8*>(&pbA1[pbr]);
            oA0 = __builtin_amdgcn_mfma_f32_16x16x32_bf16(pf0, v0, oA0, 0, 0, 0);
            oA1 = __builtin_amdgcn_mfma_f32_16x16x32_bf16(pf0, v1, oA1, 0, 0, 0);
            oA0 = __builtin_amdgcn_mfma_f32_16x16x32_bf16(pf1, v2, oA0, 0, 0, 0);
            oA1 = __builtin_amdgcn_mfma_f32_16x16x32_bf16(pf1, v3, oA1, 0, 0, 0);
        }

        // ================= strip B (rows i0+16..i0+31) ==============
        {
            f32x4 s0 = __builtin_amdgcn_mfma_f32_16x16x32_bf16(qfB, k0, zero, 0, 0, 0);
            f32x4 s1 = __builtin_amdgcn_mfma_f32_16x16x32_bf16(qfB, k1, zero, 0, 0, 0);
            f32x4 s2 = __builtin_amdgcn_mfma_f32_16x16x32_bf16(qfB, k2, zero, 0, 0, 0);
            f32x4 s3 = __builtin_amdgcn_mfma_f32_16x16x32_bf16(qfB, k3, zero, 0, 0, 0);
            f32x4 q0 = __builtin_amdgcn_mfma_f32_16x16x32_bf16(qfB, em, zero, 0, 0, 0);
            f32x4 q1 = __builtin_amdgcn_mfma_f32_16x16x32_bf16(qfB, e0, zero, 0, 0, 0);
            f32x4 q2 = __builtin_amdgcn_mfma_f32_16x16x32_bf16(qfB, e1, zero, 0, 0, 0);
            f32x4 q3 = __builtin_amdgcn_mfma_f32_16x16x32_bf16(qfB, e2, zero, 0, 0, 0);
            f32x4 q4 = __builtin_amdgcn_mfma_f32_16x16x32_bf16(qfB, e3, zero, 0, 0, 0);
            float p0[4], p1[4], p2[4], p3[4];
            #pragma unroll
            for (int r = 0; r < 4; ++r) {
                float f0 = bperm_f(addr4[r], q0[r]);
                float f1 = bperm_f(addr4[r], q1[r]);
                float f2 = bperm_f(addr4[r], q2[r]);
                float f3 = bperm_f(addr4[r], q3[r]);
                float f4 = bperm_f(addr4[r], q4[r]);
                p0[r] = EXP2F(s0[r] + (cond[r] ? f0 : f1));
                p1[r] = EXP2F(s1[r] + (cond[r] ? f1 : f2));
                p2[r] = EXP2F(s2[r] + (cond[r] ? f2 : f3));
                p3[r] = EXP2F(s3[r] + (cond[r] ? f3 : f4));
                lsumB[r] += (p0[r] + p1[r]) + (p2[r] + p3[r]);
            }
            #pragma unroll
            for (int r = 0; r < 4; ++r) {
                pbB0[pbw + 20 * r] = pack_bf16(p0[r], p1[r]);
                pbB1[pbw + 20 * r] = pack_bf16(p2[r], p3[r]);
            }
            bf16x8 pf0 = *reinterpret_cast<const bf16x8*>(&pbB0[pbr]);
            bf16x8 pf1 = *reinterpret_cast<const bf16x8*>(&pbB1[pbr]);
            oB0 = __builtin_amdgcn_mfma_f32_16x16x32_bf16(pf0, v0, oB0, 0, 0, 0);
            oB1 = __builtin_amdgcn_mfma_f32_16x16x32_bf16(pf0, v1, oB1, 0, 0, 0);
            oB0 = __builtin_amdgcn_mfma_f32_16x16x32_bf16(pf1, v2, oB0, 0, 0, 0);
            oB1 = __builtin_amdgcn_mfma_f32_16x16x32_bf16(pf1, v3, oB1, 0, 0, 0);
        }
    }

    #pragma unroll
    for (int r = 0; r < 4; ++r) {
        float va = lsumA[r], vb = lsumB[r];
        va += __shfl_xor(va, 1, 64);  vb += __shfl_xor(vb, 1, 64);
        va += __shfl_xor(va, 2, 64);  vb += __shfl_xor(vb, 2, 64);
        va += __shfl_xor(va, 4, 64);  vb += __shfl_xor(vb, 4, 64);
        va += __shfl_xor(va, 8, 64);  vb += __shfl_xor(vb, 8, 64);
        lsumA[r] = 1.0f / va;
        lsumB[r] = 1.0f / vb;
    }
    #pragma unroll
    for (int r = 0; r < 4; ++r) {
        const int srowA = i0 + quad * 4 + r;
        float* opA = out + ((size_t)b * Ss + srowA) * Ee + h * Dd;
        opA[li]      = oA0[r] * lsumA[r];
        opA[16 + li] = oA1[r] * lsumA[r];
        float* opB = opA + 16 * Ee;          // srowA + 16
        opB[li]      = oB0[r] * lsumB[r];
        opB[16 + li] = oB1[r] * lsumB[r];
    }
}

extern "C" void kernel_launch(void* const* d_in, const int* in_sizes, int n_in,
                              void* d_out, int out_size, void* d_ws, size_t ws_size,
                              hipStream_t stream) {
    const float* x  = (const float*)d_in[0];
    const float* Wq = (const float*)d_in[1];
    const float* Wk = (const float*)d_in[2];
    const float* Wv = (const float*)d_in[3];
    const float* Er = (const float*)d_in[4];
    float* out = (float*)d_out;

    // ws layout (bf16 elements; all offsets 16B-aligned)
    __hip_bfloat16* erb = reinterpret_cast<__hip_bfloat16*>(d_ws);  // [2048][32]
    __hip_bfloat16* Qs  = erb + 65536;
    __hip_bfloat16* Kh  = Qs  + (size_t)Bb * Hh * Ss * Dd;
    __hip_bfloat16* Vt  = Kh  + (size_t)Bb * Hh * Ss * Dd;

    proj_kernel<<<dim3(832), 256, 0, stream>>>(
        x, Wq, Wk, Wv, Er,
        reinterpret_cast<unsigned*>(Qs), reinterpret_cast<unsigned*>(Kh),
        reinterpret_cast<unsigned*>(Vt), reinterpret_cast<unsigned*>(erb));
    attn_kernel<<<dim3(1024), 256, 0, stream>>>(Qs, Kh, Vt, erb, out);
}